// Round 11
// baseline (48.875 us; speedup 1.0000x reference)
//
#include <hip/hip_runtime.h>
#include <stdint.h>

#define R_ 512
#define D_ 1024
#define G_ 16
#define NT 256

typedef __attribute__((ext_vector_type(8))) short short8;
typedef __attribute__((ext_vector_type(4))) float floatx4;

#if __has_builtin(__builtin_amdgcn_fractf)
#define FRACT(x) __builtin_amdgcn_fractf(x)
#else
#define FRACT(x) ((x) - floorf(x))
#endif

// bit-trick packed f32->bf16 (round-half-up); PROVEN on this HW (rounds 6-8).
// NOTE: v_cvt_pk_bf16_f32 inline asm was tried (r9/r10) and gives WRONG packing
// on gfx950 here -> absmax 1.3. Do not reintroduce.
__device__ __forceinline__ unsigned pk2bf(float a, float b) {
    unsigned ua = __builtin_bit_cast(unsigned, a) + 0x8000u;
    unsigned ub = __builtin_bit_cast(unsigned, b) + 0x8000u;
    return (ub & 0xFFFF0000u) | (ua >> 16);
}
__device__ __forceinline__ unsigned short f2bf(float a) {
    return (unsigned short)((__builtin_bit_cast(unsigned, a) + 0x8000u) >> 16);
}

// ---------- kernel 0: W transpose->bf16 + geo frag + box params ----------
__global__ __launch_bounds__(256) void prep_kernel(
    const float* __restrict__ Wq, const float* __restrict__ Wk,
    const float* __restrict__ Wv, const float* __restrict__ geo_w,
    const float* __restrict__ boxes,
    unsigned short* __restrict__ WTb, unsigned short* __restrict__ geoF,
    float4* __restrict__ bp4, float2* __restrict__ bp2, int NR)
{
    const int b = blockIdx.x, t = threadIdx.x;
    if (b < 48) {
        __shared__ float s[64][65];
        const int mat = b >> 4, rblk = b & 15;
        const float* Wsrc = (mat == 0) ? Wq : (mat == 1) ? Wk : Wv;
        const int d0 = rblk * 64;
        #pragma unroll
        for (int i = 0; i < 16; i++) {
            int e = t + i * 256;
            s[e >> 6][e & 63] = Wsrc[(size_t)(d0 + (e >> 6)) * 64 + (e & 63)];
        }
        __syncthreads();
        #pragma unroll
        for (int i = 0; i < 16; i++) {
            int e = t + i * 256;
            int c = e >> 6, r = e & 63;
            WTb[(size_t)(mat * 64 + c) * 1024 + d0 + r] = f2bf(s[r][c]);
        }
    } else if (b == 48) {
        #pragma unroll
        for (int i = 0; i < 4; i++) {
            int idx = t * 4 + i;
            int h = idx >> 9, rem = idx & 511, ll = rem >> 3, j = rem & 7;
            int e = h * 32 + (ll >> 4) * 8 + j, cc = ll & 15;
            geoF[idx] = f2bf(geo_w[e * G_ + cc]);
        }
    } else {
        int r = (b - 49) * 256 + t;
        if (r < NR) {
            float ymin = boxes[r*4+0], xmin = boxes[r*4+1];
            float ymax = boxes[r*4+2], xmax = boxes[r*4+3];
            float h = ymax - ymin + 1.0f, w = xmax - xmin + 1.0f;
            bp4[r] = make_float4(0.5f * (ymin + ymax), 0.5f * (xmin + xmax),
                                 __logf(h), __logf(w));
            bp2[r] = make_float2(1.0f / h, 1.0f / w);
        }
    }
}

// ---------- kernel 1: QKV projection via MFMA ----------
__global__ __launch_bounds__(256) void proj_kernel(
    const float* __restrict__ feat, const unsigned short* __restrict__ WTb,
    const float* __restrict__ bq, const float* __restrict__ bk,
    const float* __restrict__ bv,
    unsigned short* __restrict__ qd16, unsigned short* __restrict__ kb16,
    unsigned short* __restrict__ vT16)
{
    __shared__ __align__(16) unsigned short s_A[16][1032];

    const int t = threadIdx.x, l = t & 63, w = t >> 6;
    const int mb = blockIdx.x / 3, ng = blockIdx.x % 3;
    const long row0 = (long)mb * 16;

    const float4* f4 = (const float4*)(feat + row0 * D_);
    #pragma unroll
    for (int i = 0; i < 16; i++) {
        int e = t + i * 256;
        int row = e >> 8, c4 = e & 255;
        float4 v = f4[e];
        uint2 pk;
        pk.x = pk2bf(v.x, v.y);
        pk.y = pk2bf(v.z, v.w);
        *(uint2*)&s_A[row][c4 * 4] = pk;
    }
    __syncthreads();

    const int lc = l & 15, q = l >> 4;
    const int gcol = (ng * 4 + w) * 16 + lc;       // 0..191
    const unsigned short* bptr = WTb + (size_t)gcol * 1024 + q * 8;

    floatx4 acc = {0.f, 0.f, 0.f, 0.f};
    #pragma unroll 8
    for (int k0 = 0; k0 < 1024; k0 += 32) {
        short8 a  = *(const short8*)&s_A[lc][k0 + q * 8];
        short8 bb = *(const short8*)(bptr + k0);
        acc = __builtin_amdgcn_mfma_f32_16x16x32_bf16(a, bb, acc, 0, 0, 0);
    }

    const int mat = gcol >> 6, mcol = gcol & 63;
    const float* B = (mat == 0) ? bq : (mat == 1) ? bk : bv;
    const float bias = B[mcol];
    #pragma unroll
    for (int r = 0; r < 4; r++) {
        long gr = row0 + q * 4 + r;
        float val = acc[r] + bias;
        if (mat == 0)      qd16[gr * 64 + mcol] = f2bf(0.5f * val);
        else if (mat == 1) kb16[gr * 64 + mcol] = f2bf(val);
        else               vT16[((size_t)((gr >> 9) * 64 + mcol)) * 512 + (gr & 511)] = f2bf(val);
    }
}

// ---------- kernel 2: fused relation, 2 q-rows per block, single-pass softmax ----------
__global__ __launch_bounds__(256, 4) void relation_kernel(
    const float* __restrict__ feat, const float* __restrict__ geo_b,
    const unsigned short* __restrict__ geoF, const unsigned short* __restrict__ qd16,
    const unsigned short* __restrict__ kb16, const unsigned short* __restrict__ vT16,
    const float4* __restrict__ bp4, const float2* __restrict__ bp2,
    float* __restrict__ out)
{
    __shared__ __align__(16) unsigned short s_p[2][16][520];
    __shared__ float s_reds[2][4][16];

    const int t = threadIdx.x;
    const int l = t & 63;
    const int w = t >> 6;
    const int c = l & 15;
    const int quad = l >> 4;
    const int nqA = blockIdx.x * 2, nqB = nqA + 1;
    const int n = nqA >> 9;

    const float4 qbA = bp4[nqA], qbB = bp4[nqB];
    const float2 qiA = bp2[nqA], qiB = bp2[nqB];
    const float gbias = geo_b[c];
    const floatx4 ginit = {gbias, gbias, gbias, gbias};

    short8 bgeo0 = *(const short8*)(geoF + l * 8);
    short8 bgeo1 = *(const short8*)(geoF + 512 + l * 8);

    const bool act = (quad == ((c >> 1) & 3));
    const int hsel = c >> 3, jhalf = c & 1;
    uint2 qvA = *(const uint2*)(qd16 + (size_t)nqA * 64 + c * 4);
    uint2 qvB = *(const uint2*)(qd16 + (size_t)nqB * 64 + c * 4);
    short qA[4] = {(short)(qvA.x & 0xFFFF), (short)(qvA.x >> 16),
                   (short)(qvA.y & 0xFFFF), (short)(qvA.y >> 16)};
    short qB[4] = {(short)(qvB.x & 0xFFFF), (short)(qvB.x >> 16),
                   (short)(qvB.y & 0xFFFF), (short)(qvB.y >> 16)};
    short8 bqfA0, bqfA1, bqfB0, bqfB1;
    #pragma unroll
    for (int j = 0; j < 8; j++) {
        bool on0 = act && (hsel == 0) && ((j >> 2) == jhalf);
        bool on1 = act && (hsel == 1) && ((j >> 2) == jhalf);
        bqfA0[j] = on0 ? qA[j & 3] : (short)0;
        bqfA1[j] = on1 ? qA[j & 3] : (short)0;
        bqfB0[j] = on0 ? qB[j & 3] : (short)0;
        bqfB1[j] = on1 ? qB[j & 3] : (short)0;
    }

    const float C8[8] = {
        15.91549431f,
        15.91549431f * 0.4216965034f,
        15.91549431f * 0.1778279410f,
        15.91549431f * 0.0749894209f,
        15.91549431f * 0.0316227766f,
        15.91549431f * 0.0133352143f,
        15.91549431f * 0.0056234133f,
        15.91549431f * 0.0023713737f };

    // cos(2πx) = sin(2π·fract(x+0.25)); v_sin_f32 REQUIRES fract-reduced input
    // on gfx950 (round-9 regression evidence).
    const float offs = (quad & 1) ? 0.25f : 0.0f;
    const bool qlow = (quad < 2);

    float sumA = 0.f, sumB = 0.f;
    const int krow0 = n * R_ + w * 128;

    #pragma unroll
    for (int ti = 0; ti < 8; ti++) {
        float4 kb = bp4[krow0 + ti * 16 + c];

        float aA  = qlow ? (qbA.x - kb.x) * qiA.x : (qbA.y - kb.y) * qiA.y;
        float pAa = __logf(fmaxf(aA, 1e-5f));
        float pAb = qlow ? (qbA.z - kb.z) : (qbA.w - kb.w);
        float aB  = qlow ? (qbB.x - kb.x) * qiB.x : (qbB.y - kb.y) * qiB.y;
        float pBa = __logf(fmaxf(aB, 1e-5f));
        float pBb = qlow ? (qbB.z - kb.z) : (qbB.w - kb.w);

        uint4 uA0, uA1, uB0, uB1;
        #pragma unroll
        for (int jj = 0; jj < 4; jj++) {
            float r0, r1;
            r0 = FRACT(fmaf(pAa, C8[2*jj],   offs));
            r1 = FRACT(fmaf(pAa, C8[2*jj+1], offs));
            (&uA0.x)[jj] = pk2bf(__builtin_amdgcn_sinf(r0), __builtin_amdgcn_sinf(r1));
            r0 = FRACT(fmaf(pAb, C8[2*jj],   offs));
            r1 = FRACT(fmaf(pAb, C8[2*jj+1], offs));
            (&uA1.x)[jj] = pk2bf(__builtin_amdgcn_sinf(r0), __builtin_amdgcn_sinf(r1));
            r0 = FRACT(fmaf(pBa, C8[2*jj],   offs));
            r1 = FRACT(fmaf(pBa, C8[2*jj+1], offs));
            (&uB0.x)[jj] = pk2bf(__builtin_amdgcn_sinf(r0), __builtin_amdgcn_sinf(r1));
            r0 = FRACT(fmaf(pBb, C8[2*jj],   offs));
            r1 = FRACT(fmaf(pBb, C8[2*jj+1], offs));
            (&uB1.x)[jj] = pk2bf(__builtin_amdgcn_sinf(r0), __builtin_amdgcn_sinf(r1));
        }
        short8 aeA0 = __builtin_bit_cast(short8, uA0);
        short8 aeA1 = __builtin_bit_cast(short8, uA1);
        short8 aeB0 = __builtin_bit_cast(short8, uB0);
        short8 aeB1 = __builtin_bit_cast(short8, uB1);

        const unsigned short* kr = kb16 + (size_t)(krow0 + ti * 16 + c) * 64;
        short8 ak0 = *(const short8*)(kr + quad * 8);
        short8 ak1 = *(const short8*)(kr + 32 + quad * 8);

        floatx4 accgA = ginit, acckA = {0,0,0,0};
        floatx4 accgB = ginit, acckB = {0,0,0,0};
        accgA = __builtin_amdgcn_mfma_f32_16x16x32_bf16(aeA0, bgeo0, accgA, 0, 0, 0);
        accgA = __builtin_amdgcn_mfma_f32_16x16x32_bf16(aeA1, bgeo1, accgA, 0, 0, 0);
        accgB = __builtin_amdgcn_mfma_f32_16x16x32_bf16(aeB0, bgeo0, accgB, 0, 0, 0);
        accgB = __builtin_amdgcn_mfma_f32_16x16x32_bf16(aeB1, bgeo1, accgB, 0, 0, 0);
        acckA = __builtin_amdgcn_mfma_f32_16x16x32_bf16(ak0, bqfA0, acckA, 0, 0, 0);
        acckA = __builtin_amdgcn_mfma_f32_16x16x32_bf16(ak1, bqfA1, acckA, 0, 0, 0);
        acckB = __builtin_amdgcn_mfma_f32_16x16x32_bf16(ak0, bqfB0, acckB, 0, 0, 0);
        acckB = __builtin_amdgcn_mfma_f32_16x16x32_bf16(ak1, bqfB1, acckB, 0, 0, 0);

        // e = relu-clamped geometry weight * exp(appearance)
        int k0 = w * 128 + ti * 16 + quad * 4;
        float eA0 = fmaxf(accgA[0], 1e-6f) * __expf(acckA[0]);
        float eA1 = fmaxf(accgA[1], 1e-6f) * __expf(acckA[1]);
        float eA2 = fmaxf(accgA[2], 1e-6f) * __expf(acckA[2]);
        float eA3 = fmaxf(accgA[3], 1e-6f) * __expf(acckA[3]);
        sumA += (eA0 + eA1) + (eA2 + eA3);
        uint2 pkA; pkA.x = pk2bf(eA0, eA1); pkA.y = pk2bf(eA2, eA3);
        *(uint2*)&s_p[0][c][k0] = pkA;

        float eB0 = fmaxf(accgB[0], 1e-6f) * __expf(acckB[0]);
        float eB1 = fmaxf(accgB[1], 1e-6f) * __expf(acckB[1]);
        float eB2 = fmaxf(accgB[2], 1e-6f) * __expf(acckB[2]);
        float eB3 = fmaxf(accgB[3], 1e-6f) * __expf(acckB[3]);
        sumB += (eB0 + eB1) + (eB2 + eB3);
        uint2 pkB; pkB.x = pk2bf(eB0, eB1); pkB.y = pk2bf(eB2, eB3);
        *(uint2*)&s_p[1][c][k0] = pkB;
    }

    sumA += __shfl_xor(sumA, 16);
    sumA += __shfl_xor(sumA, 32);
    sumB += __shfl_xor(sumB, 16);
    sumB += __shfl_xor(sumB, 32);
    if (l < 16) { s_reds[0][w][l] = sumA; s_reds[1][w][l] = sumB; }
    __syncthreads();

    floatx4 accpA = {0,0,0,0}, accpB = {0,0,0,0};
    const unsigned short* vrow = vT16 + ((size_t)(n * 64 + w * 16 + c)) * 512;
    #pragma unroll
    for (int ks = 0; ks < 16; ks++) {
        short8 bv8 = *(const short8*)(vrow + ks * 32 + quad * 8);
        short8 apA = *(const short8*)(&s_p[0][c][ks * 32 + quad * 8]);
        short8 apB = *(const short8*)(&s_p[1][c][ks * 32 + quad * 8]);
        accpA = __builtin_amdgcn_mfma_f32_16x16x32_bf16(apA, bv8, accpA, 0, 0, 0);
        accpB = __builtin_amdgcn_mfma_f32_16x16x32_bf16(apB, bv8, accpB, 0, 0, 0);
    }

    #pragma unroll
    for (int r = 0; r < 4; r++) {
        int gg = quad * 4 + r;
        float sA = (s_reds[0][0][gg] + s_reds[0][1][gg]) + (s_reds[0][2][gg] + s_reds[0][3][gg]);
        float sB = (s_reds[1][0][gg] + s_reds[1][1][gg]) + (s_reds[1][2][gg] + s_reds[1][3][gg]);
        size_t oA = (size_t)nqA * D_ + (size_t)gg * 64 + w * 16 + c;
        size_t oB = (size_t)nqB * D_ + (size_t)gg * 64 + w * 16 + c;
        out[oA] = feat[oA] + accpA[r] / sA;
        out[oB] = feat[oB] + accpB[r] / sB;
    }
}

extern "C" void kernel_launch(void* const* d_in, const int* in_sizes, int n_in,
                              void* d_out, int out_size, void* d_ws, size_t ws_size,
                              hipStream_t stream) {
    const float* feat  = (const float*)d_in[0];
    const float* boxes = (const float*)d_in[1];
    const float* geo_w = (const float*)d_in[2];
    const float* geo_b = (const float*)d_in[3];
    const float* Wq    = (const float*)d_in[4];
    const float* bq    = (const float*)d_in[5];
    const float* Wk    = (const float*)d_in[6];
    const float* bk    = (const float*)d_in[7];
    const float* Wv    = (const float*)d_in[8];
    const float* bv    = (const float*)d_in[9];
    float* out = (float*)d_out;

    const int N  = in_sizes[0] / (R_ * D_);
    const int NR = N * R_;

    float4* bp4 = (float4*)d_ws;
    float2* bp2 = (float2*)(bp4 + NR);
    unsigned short* kb16 = (unsigned short*)(bp2 + NR);
    unsigned short* vT16 = kb16 + (size_t)NR * 64;
    unsigned short* qd16 = vT16 + (size_t)NR * 64;
    unsigned short* WTb  = qd16 + (size_t)NR * 64;
    unsigned short* geoF = WTb + (size_t)192 * 1024;

    prep_kernel<<<dim3(49 + (NR + 255) / 256), dim3(NT), 0, stream>>>(
        Wq, Wk, Wv, geo_w, boxes, WTb, geoF, bp4, bp2, NR);
    proj_kernel<<<dim3((NR / 16) * 3), dim3(NT), 0, stream>>>(
        feat, WTb, bq, bk, bv, qd16, kb16, vT16);
    relation_kernel<<<dim3(NR / 2), dim3(NT), 0, stream>>>(
        feat, geo_b, geoF, qd16, kb16, vT16, bp4, bp2, out);
}